// Round 4
// baseline (432.058 us; speedup 1.0000x reference)
//
#include <hip/hip_runtime.h>
#include <stdint.h>

#define B_TOK 8192
#define DIM   2048
#define NE    8
#define BM 128
#define BN 128
#define BK 64
#define MG 8   // m-groups in GEMM grid

typedef __bf16 bf16x8 __attribute__((ext_vector_type(8)));
typedef float  f32x4  __attribute__((ext_vector_type(4)));

__device__ __forceinline__ unsigned short f2b(float f) {
  unsigned u = __builtin_bit_cast(unsigned, f);
  u += 0x7fffu + ((u >> 16) & 1u);   // round-to-nearest-even
  return (unsigned short)(u >> 16);
}
__device__ __forceinline__ uint2 pack4(float4 v) {
  uint2 r;
  r.x = (unsigned)f2b(v.x) | ((unsigned)f2b(v.y) << 16);
  r.y = (unsigned)f2b(v.z) | ((unsigned)f2b(v.w) << 16);
  return r;
}
__device__ __forceinline__ void gload16(const void* g, void* l) {
  __builtin_amdgcn_global_load_lds(
      (const __attribute__((address_space(1))) void*)g,
      (__attribute__((address_space(3))) void*)l, 16, 0, 0);
}

// ---------------- fused prepass: gate (blocks 0..2047) + We cvt ------------
// Gate: one wave per token, exact f64 logits, NO unroll-hoist spills.
// Cvt:  blocks 2048.. convert We f32 -> bf16, 8 elems/thread.
template <bool WINP>
__global__ __launch_bounds__(256) void prepass(
    const float* __restrict__ x, const float* __restrict__ y,
    const float* __restrict__ gW, const float* __restrict__ gb,
    const float* __restrict__ We,
    int* __restrict__ eid, unsigned short* __restrict__ inpB,
    unsigned short* __restrict__ WeB) {
  const int bid = blockIdx.x;
  const int tid = threadIdx.x;
  if (WINP && bid >= 2048) {
    // We conversion: 16384 blocks x 256 thr x 8 floats = 33.55M elems
    size_t base = (size_t)(bid - 2048) * 2048 + (size_t)tid * 8;
    float4 v0 = *(const float4*)(We + base);
    float4 v1 = *(const float4*)(We + base + 4);
    uint2 a = pack4(v0), b = pack4(v1);
    uint4 r; r.x = a.x; r.y = a.y; r.z = b.x; r.w = b.y;
    *(uint4*)(WeB + base) = r;
    return;
  }
  const int ln = tid & 63;
  const int token = bid * 4 + (tid >> 6);

  double acc[NE];
#pragma unroll
  for (int e = 0; e < NE; ++e) acc[e] = 0.0;

  const float* rowx = x + (size_t)token * 1024;
  const float* rowy = y + (size_t)token * 1024;

#pragma unroll 1          // keep loads per-iter; full unroll spilled to scratch
  for (int it = 0; it < 8; ++it) {
    const int d = it * 256 + ln * 4;     // wave-uniform range per it
    const float* src = (d < 1024) ? (rowx + d) : (rowy + d - 1024);
    float4 v = *(const float4*)src;
    if (WINP)
      *(uint2*)(inpB + (size_t)token * DIM + d) = pack4(v);
    double vx = v.x, vy = v.y, vz = v.z, vw = v.w;
#pragma unroll
    for (int e = 0; e < NE; ++e) {
      float4 g = *(const float4*)(gW + e * DIM + d);
      acc[e] += vx * (double)g.x + vy * (double)g.y +
                vz * (double)g.z + vw * (double)g.w;
    }
  }
#pragma unroll
  for (int e = 0; e < NE; ++e) {
#pragma unroll
    for (int off = 32; off >= 1; off >>= 1) acc[e] += __shfl_xor(acc[e], off, 64);
  }
  if (ln == 0) {
    int best = 0;
    double bv = acc[0] + (double)gb[0];
#pragma unroll
    for (int e = 1; e < NE; ++e) {
      double v = acc[e] + (double)gb[e];
      if (v > bv) { bv = v; best = e; }   // strict > keeps lowest index on ties
    }
    eid[token] = best;
  }
}

// ---------------- bucketize: deterministic token->expert lists -------------
__global__ __launch_bounds__(256) void bucketize(const int* __restrict__ eid,
                                                 int* __restrict__ counts,
                                                 int* __restrict__ perm) {
  const int e = blockIdx.x;
  const int tid = threadIdx.x, ln = tid & 63, wv = tid >> 6;
  __shared__ int wsum[4];
  __shared__ int basev;
  if (tid == 0) basev = 0;
  __syncthreads();
  for (int t0 = 0; t0 < B_TOK; t0 += 256) {
    int t = t0 + tid;
    bool m = (eid[t] == e);
    unsigned long long mk = __ballot(m);
    int pre = __popcll(mk & ((1ull << ln) - 1ull));
    if (ln == 0) wsum[wv] = __popcll(mk);
    __syncthreads();
    int off = basev;
    for (int w = 0; w < wv; ++w) off += wsum[w];
    if (m) perm[e * B_TOK + off + pre] = t;
    __syncthreads();
    if (tid == 0) basev += wsum[0] + wsum[1] + wsum[2] + wsum[3];
    __syncthreads();
  }
  if (tid == 0) counts[e] = basev;
}

// ---------------- grouped GEMM: out[tok] = We[e] @ inp[tok] + be[e] --------
// Grid (16 n-tiles, MG m-groups, 8 experts) — live blocks only; each block
// loops m-tiles mt, mt+MG, ... LDS XOR-swizzled (slot c = chunk ^ (row&7)).
template <bool PRE>
__global__ __launch_bounds__(256) void moe_gemm(
    const float* __restrict__ x,
    const float* __restrict__ y,
    const float* __restrict__ We,
    const float* __restrict__ be,
    const unsigned short* __restrict__ inpB,
    const unsigned short* __restrict__ WeB,
    const int* __restrict__ counts,
    const int* __restrict__ perm,
    float* __restrict__ out) {
  __shared__ unsigned short As[BM * BK];
  __shared__ unsigned short Bs[BN * BK];
  __shared__ int tokLds[BM];

  const int e = blockIdx.z;
  const int cnt = counts[e];
  const int n0 = blockIdx.x * BN;

  const int tid = threadIdx.x;
  const int ln = tid & 63;
  const int wv = tid >> 6;
  const int wm = wv & 1, wn = wv >> 1;
  const int cS = (ln & 7) ^ ((ln >> 3) & 7);

  const unsigned short* wbbase = WeB + (size_t)e * DIM * DIM;
  const float* wfbase = We + (size_t)e * DIM * DIM;

  float bias[4]; int col[4];
#pragma unroll
  for (int j = 0; j < 4; ++j) {
    col[j] = n0 + wn * 64 + j * 16 + (ln & 15);
    bias[j] = be[e * DIM + col[j]];
  }
  int rowB[4];
#pragma unroll
  for (int j = 0; j < 4; ++j) rowB[j] = (wv * 4 + j) * 8 + (ln >> 3);

  for (int mt = blockIdx.y; mt * BM < cnt; mt += MG) {
    const int m0 = mt * BM;
    __syncthreads();               // protect tokLds from prev epilogue readers
    if (tid < BM) {
      int r = m0 + tid;
      tokLds[tid] = perm[e * B_TOK + (r < cnt ? r : cnt - 1)];
    }
    __syncthreads();
    int tokA[4];
#pragma unroll
    for (int j = 0; j < 4; ++j) tokA[j] = tokLds[rowB[j]];

    f32x4 acc[4][4];
#pragma unroll
    for (int i = 0; i < 4; ++i)
#pragma unroll
      for (int j = 0; j < 4; ++j) acc[i][j] = (f32x4){0.f, 0.f, 0.f, 0.f};

    for (int k0 = 0; k0 < DIM; k0 += BK) {
      __syncthreads();
      if constexpr (PRE) {
#pragma unroll
        for (int j = 0; j < 4; ++j) {
          gload16(inpB + (size_t)tokA[j] * DIM + k0 + cS * 8,
                  &As[(wv * 4 + j) * 512]);
          gload16(wbbase + (size_t)(n0 + rowB[j]) * DIM + k0 + cS * 8,
                  &Bs[(wv * 4 + j) * 512]);
        }
      } else {
        const float* ab = (k0 < 1024) ? x : y;
        const int kk = k0 & 1023;
#pragma unroll
        for (int i = 0; i < 8; ++i) {
          int li = i * 256 + tid;            // 2048 float4 per tile
          int row = li >> 4, k4 = li & 15;
          int chunk = k4 >> 1, half = k4 & 1;
          int slot = (chunk ^ (row & 7)) * 2 + half;
          int tok = tokLds[row];
          float4 va = *(const float4*)(ab + (size_t)tok * 1024 + kk + k4 * 4);
          *(uint2*)&As[row * BK + slot * 4] = pack4(va);
          float4 vb = *(const float4*)(wfbase + (size_t)(n0 + row) * DIM + k0 + k4 * 4);
          *(uint2*)&Bs[row * BK + slot * 4] = pack4(vb);
        }
      }
      __syncthreads();

#pragma unroll
      for (int ks = 0; ks < 2; ++ks) {
        bf16x8 av[4], bv[4];
#pragma unroll
        for (int i = 0; i < 4; ++i) {
          int rA = wm * 64 + i * 16 + (ln & 15);
          int c = ks * 4 + (ln >> 4);
          av[i] = *(const bf16x8*)&As[rA * BK + (c ^ (rA & 7)) * 8];
        }
#pragma unroll
        for (int j = 0; j < 4; ++j) {
          int rB = wn * 64 + j * 16 + (ln & 15);
          int c = ks * 4 + (ln >> 4);
          bv[j] = *(const bf16x8*)&Bs[rB * BK + (c ^ (rB & 7)) * 8];
        }
#pragma unroll
        for (int i = 0; i < 4; ++i)
#pragma unroll
          for (int j = 0; j < 4; ++j)
            acc[i][j] = __builtin_amdgcn_mfma_f32_16x16x32_bf16(av[i], bv[j], acc[i][j], 0, 0, 0);
      }
    }

    // epilogue: += bias, scatter rows by token id, f32 store
#pragma unroll
    for (int i = 0; i < 4; ++i) {
      int rbase = wm * 64 + i * 16 + ((ln >> 4) << 2);
#pragma unroll
      for (int r = 0; r < 4; ++r) {
        int rl = rbase + r;
        if (m0 + rl < cnt) {
          size_t t = (size_t)tokLds[rl];
#pragma unroll
          for (int j = 0; j < 4; ++j)
            out[t * DIM + col[j]] = acc[i][j][r] + bias[j];
        }
      }
    }
  }
}

extern "C" void kernel_launch(void* const* d_in, const int* in_sizes, int n_in,
                              void* d_out, int out_size, void* d_ws, size_t ws_size,
                              hipStream_t stream) {
  const float* x  = (const float*)d_in[0];
  const float* y  = (const float*)d_in[1];
  const float* We = (const float*)d_in[2];
  const float* be = (const float*)d_in[3];
  const float* gW = (const float*)d_in[4];
  const float* gb = (const float*)d_in[5];
  float* out = (float*)d_out;

  char* ws = (char*)d_ws;
  int* counts = (int*)ws;                                   // @0, 8 ints
  int* eid    = (int*)(ws + 256);                           // 8192 ints
  int* perm   = (int*)(ws + 33024);                         // 8*8192 ints
  unsigned short* inpB = (unsigned short*)(ws + 295168);    // 33.5 MB bf16 [8192][2048]
  unsigned short* WeB  = (unsigned short*)(ws + 33849600);  // 67.1 MB bf16 [8][2048][2048]
  const size_t needed = 33849600ull + 67108864ull;

  if (ws_size >= needed) {
    prepass<true><<<dim3(2048 + 16384), 256, 0, stream>>>(x, y, gW, gb, We, eid, inpB, WeB);
    bucketize<<<dim3(NE), 256, 0, stream>>>(eid, counts, perm);
    moe_gemm<true><<<dim3(DIM / BN, MG, NE), 256, 0, stream>>>(
        x, y, We, be, inpB, WeB, counts, perm, out);
  } else {
    prepass<false><<<dim3(2048), 256, 0, stream>>>(x, y, gW, gb, We, eid, nullptr, nullptr);
    bucketize<<<dim3(NE), 256, 0, stream>>>(eid, counts, perm);
    moe_gemm<false><<<dim3(DIM / BN, MG, NE), 256, 0, stream>>>(
        x, y, We, be, nullptr, nullptr, counts, perm, out);
  }
}